// Round 3
// baseline (23568.138 us; speedup 1.0000x reference)
//
#include <hip/hip_runtime.h>
#include <hip/hip_bf16.h>

#define S_LEN 4096
#define EDIM  300
#define HDIM  512
#define G4    2048
#define NTAG  5
#define NEGV  -10000.0f
#define START_TAG 3
#define STOP_TAG  4
#define L2E 1.4426950408889634f
#define LN2 0.6931471805599453f
#define POIS_U 0x7F7F7F7Fu

typedef __attribute__((ext_vector_type(4))) float f32x4;

// ---------- workspace layout (bytes) ----------
static constexpr size_t OFF_XP    = 0;                                   // bf16 [2][S][2048]
static constexpr size_t XP_BYTES  = (size_t)2 * S_LEN * G4 * 2;
static constexpr size_t OFF_HBS   = OFF_XP + XP_BYTES;                   // f32 [2][S][512] poison-polled h history
static constexpr size_t HBS_BYTES = (size_t)2 * S_LEN * HDIM * 4;
static constexpr size_t OFF_FEATS = OFF_HBS + HBS_BYTES;                 // f32 [S][5]
static constexpr size_t OFF_MPART = OFF_FEATS + (size_t)S_LEN * NTAG * 4;// f32 [64][25]
static constexpr size_t OFF_GOLD  = OFF_MPART + (size_t)64 * 25 * 4;     // f32 [64]
static constexpr size_t WS_NEEDED = OFF_GOLD + 256;

// ---------- helpers ----------
static __device__ __forceinline__ float fexp_(float x){ return __builtin_amdgcn_exp2f(x * L2E); }
static __device__ __forceinline__ float fsig_(float x){ return __builtin_amdgcn_rcpf(1.0f + fexp_(-x)); }
static __device__ __forceinline__ float ftanh_(float x){ return 1.0f - 2.0f*__builtin_amdgcn_rcpf(fexp_(2.0f*x) + 1.0f); }

static __device__ __forceinline__ float lse5(float t0,float t1,float t2,float t3,float t4){
  float m = fmaxf(fmaxf(fmaxf(t0,t1),fmaxf(t2,t3)),t4);
  float s = __builtin_amdgcn_exp2f((t0-m)*L2E) + __builtin_amdgcn_exp2f((t1-m)*L2E)
          + __builtin_amdgcn_exp2f((t2-m)*L2E) + __builtin_amdgcn_exp2f((t3-m)*L2E)
          + __builtin_amdgcn_exp2f((t4-m)*L2E);
  return m + __builtin_amdgcn_logf(s)*LN2;
}

// C[i][j] = LSE_k(cur[i][k] + bv[k][j]); lane layout: lane = i*5+j (lanes 0..24)
static __device__ __forceinline__ float lse_mm(float cur, float bv, int i, int j){
  const float a0=__shfl(cur, i*5+0), a1=__shfl(cur, i*5+1), a2=__shfl(cur, i*5+2),
              a3=__shfl(cur, i*5+3), a4=__shfl(cur, i*5+4);
  const float c0=__shfl(bv, 0+j),  c1=__shfl(bv, 5+j),  c2=__shfl(bv, 10+j),
              c3=__shfl(bv, 15+j), c4=__shfl(bv, 20+j);
  return lse5(a0+c0, a1+c1, a2+c2, a3+c3, a4+c4);
}

// ---------- phase 0: poison-fill hbs with coherent (sc0 sc1) stores so no dirty L2 lines exist ----------
__global__ __launch_bounds__(256) void fill_poison(float* __restrict__ p, int n4){
  const int idx = blockIdx.x*blockDim.x + threadIdx.x;
  const int stride = gridDim.x*blockDim.x;
  f32x4 pv;
  pv.x = __uint_as_float(POIS_U); pv.y = __uint_as_float(POIS_U);
  pv.z = __uint_as_float(POIS_U); pv.w = __uint_as_float(POIS_U);
  for (int i = idx; i < n4; i += stride) {
    float* dst = p + (size_t)i*4;
    asm volatile("global_store_dwordx4 %0, %1, off sc0 sc1" :: "v"(dst), "v"(pv) : "memory");
  }
}

// ---------- phase A: xp[dir][s][2048] = emb[sent[s]] @ w_ih.T + (b_ih+b_hh), stored bf16 ----------
__global__ __launch_bounds__(256) void xp_gemm(
    const int* __restrict__ sentence, const float* __restrict__ emb,
    const float* __restrict__ w_ih_f, const float* __restrict__ b_ih_f, const float* __restrict__ b_hh_f,
    const float* __restrict__ w_ih_b, const float* __restrict__ b_ih_b, const float* __restrict__ b_hh_b,
    __hip_bfloat16* __restrict__ xp)
{
  __shared__ float At[32][132];
  __shared__ float Bt[32][132];
  __shared__ int sent_s[128];

  const int dir = blockIdx.y;
  const int tm = blockIdx.x & 31;
  const int tn = blockIdx.x >> 5;
  const float* __restrict__ wih = dir ? w_ih_b : w_ih_f;
  const float* __restrict__ bi  = dir ? b_ih_b : b_ih_f;
  const float* __restrict__ bh  = dir ? b_hh_b : b_hh_f;

  const int tid = threadIdx.x;
  if (tid < 128) sent_s[tid] = sentence[tm*128 + tid];

  const int ty = tid >> 4, tx = tid & 15;
  const int li = tid >> 1, lh = tid & 1;

  float acc[8][8];
#pragma unroll
  for (int i = 0; i < 8; ++i){
#pragma unroll
    for (int j = 0; j < 8; ++j) acc[i][j] = 0.0f;
  }
  __syncthreads();

  for (int kc0 = 0; kc0 < EDIM; kc0 += 32) {
    const int kw = (EDIM - kc0 < 32) ? (EDIM - kc0) : 32;
    if (kc0 + lh*16 + 16 <= EDIM) {
      const float4* pa = (const float4*)(emb + (size_t)sent_s[li]*EDIM + kc0 + lh*16);
      const float4* pb = (const float4*)(wih + (size_t)(tn*128 + li)*EDIM + kc0 + lh*16);
#pragma unroll
      for (int v = 0; v < 4; ++v) {
        const float4 a = pa[v], b = pb[v];
        const int kk = lh*16 + v*4;
        At[kk+0][li] = a.x; At[kk+1][li] = a.y; At[kk+2][li] = a.z; At[kk+3][li] = a.w;
        Bt[kk+0][li] = b.x; Bt[kk+1][li] = b.y; Bt[kk+2][li] = b.z; Bt[kk+3][li] = b.w;
      }
    } else {
#pragma unroll
      for (int jj = 0; jj < 16; ++jj) {
        const int col = kc0 + lh*16 + jj;
        float av = 0.f, bv = 0.f;
        if (col < EDIM) {
          av = emb[(size_t)sent_s[li]*EDIM + col];
          bv = wih[(size_t)(tn*128 + li)*EDIM + col];
        }
        At[lh*16+jj][li] = av;
        Bt[lh*16+jj][li] = bv;
      }
    }
    __syncthreads();
#pragma unroll 4
    for (int k = 0; k < kw; ++k) {
      const float4 a0 = *(const float4*)&At[k][ty*8];
      const float4 a1 = *(const float4*)&At[k][ty*8+4];
      const float4 b0 = *(const float4*)&Bt[k][tx*8];
      const float4 b1 = *(const float4*)&Bt[k][tx*8+4];
      const float av[8] = {a0.x,a0.y,a0.z,a0.w,a1.x,a1.y,a1.z,a1.w};
      const float bv[8] = {b0.x,b0.y,b0.z,b0.w,b1.x,b1.y,b1.z,b1.w};
#pragma unroll
      for (int i = 0; i < 8; ++i){
#pragma unroll
        for (int j = 0; j < 8; ++j) acc[i][j] = __builtin_fmaf(av[i], bv[j], acc[i][j]);
      }
    }
    __syncthreads();
  }

  const int n0 = tn*128 + tx*8;
  float bias[8];
#pragma unroll
  for (int j = 0; j < 8; ++j) bias[j] = bi[n0+j] + bh[n0+j];

  __hip_bfloat16* __restrict__ xpd = xp + (size_t)dir * S_LEN * G4;
#pragma unroll
  for (int i = 0; i < 8; ++i) {
    const int m = tm*128 + ty*8 + i;
    __hip_bfloat16 __align__(16) tmp[8];
#pragma unroll
    for (int j = 0; j < 8; ++j) tmp[j] = __float2bfloat16(acc[i][j] + bias[j]);
    *(uint4*)(xpd + (size_t)m*G4 + n0) = *(const uint4*)tmp;
  }
}

// ---------- phase B: persistent BiLSTM, poison-poll sync, weights pinned in VGPRs ----------
// 16 wgs/dir x 512 threads. Wave w_ owns units [wg*32+w_*4, +4); lane l owns h-cols [8l, 8l+8).
// No __syncthreads, no flags, no fences: h values self-signal via poison pattern.
__global__ __launch_bounds__(512, 1) void lstm_pers(
    const float* __restrict__ w_hh_f, const float* __restrict__ w_hh_b,
    const __hip_bfloat16* __restrict__ xp, float* __restrict__ hbs)
{
  const int dir = blockIdx.x >> 4;
  const int wg  = blockIdx.x & 15;
  const int tid = threadIdx.x;
  const int w_  = tid >> 6;
  const int l   = tid & 63;
  const int u   = l & 3;                 // unit tracked by this lane's gate path (lanes 0-3 are owners)
  const int gu  = wg*32 + w_*4 + u;      // global unit index

  const float* __restrict__ whh = dir ? w_hh_b : w_hh_f;
  const __hip_bfloat16* __restrict__ xpd = xp + (size_t)dir * S_LEN * G4;
  float* __restrict__ hbs_d = hbs + (size_t)dir * S_LEN * HDIM;

  // resident weights: 16 rows (4 units x 4 gates) x 8 cols. row r = 4*u_loc + g -> wv[2r], wv[2r+1].
  f32x4 wv[32];
#pragma unroll
  for (int r = 0; r < 16; ++r) {
    const int g = r & 3, ul = r >> 2;
    const int grow = g*HDIM + wg*32 + w_*4 + ul;
    const f32x4* wp = (const f32x4*)(whh + (size_t)grow*HDIM + l*8);
    wv[2*r]   = wp[0];
    wv[2*r+1] = wp[1];
  }
  // PIN: make each weight vector an asm-defined register value. The compiler
  // can no longer rematerialize them from (const restrict) memory inside the
  // loop — this is what forces true VGPR residency (round-2 failure mode).
#pragma unroll
  for (int i = 0; i < 32; ++i) asm volatile("" : "+v"(wv[i]));

  // gather lane for row r=4u+g sits at lane (u>>1) + 2*(u&1) + 4*(g>>1) + 8*(g&1)
  const int f_ = 2*(l&1) + ((l>>1)&1);

  const __hip_bfloat16* xptr = xpd + (size_t)(dir ? (S_LEN-1) : 0) * G4 + gu;
  const ptrdiff_t xstep = dir ? -(ptrdiff_t)G4 : (ptrdiff_t)G4;
  float xn0 = __bfloat162float(xptr[0*HDIM]);
  float xn1 = __bfloat162float(xptr[1*HDIM]);
  float xn2 = __bfloat162float(xptr[2*HDIM]);
  float xn3 = __bfloat162float(xptr[3*HDIM]);

  const float* psrc = hbs_d + l*8;
  float*       pdst = hbs_d + gu;
  float cst = 0.0f;

#pragma clang loop unroll(disable)
  for (int s = 0; s < S_LEN; ++s) {
    float acc[16];
    if (s == 0) {
#pragma unroll
      for (int r = 0; r < 16; ++r) acc[r] = 0.0f;
    } else {
      f32x4 pa, pb;
      const float* sp = psrc + (size_t)(s-1)*HDIM;
      for (int it = 0; it < (1<<18); ++it) {
        asm volatile(
          "global_load_dwordx4 %0, %2, off sc0 sc1\n\t"
          "global_load_dwordx4 %1, %2, off offset:16 sc0 sc1\n\t"
          "s_waitcnt vmcnt(0)"
          : "=&v"(pa), "=&v"(pb) : "v"(sp));
        const int ok = (__float_as_uint(pa.x) != POIS_U) & (__float_as_uint(pa.y) != POIS_U)
                     & (__float_as_uint(pa.z) != POIS_U) & (__float_as_uint(pa.w) != POIS_U)
                     & (__float_as_uint(pb.x) != POIS_U) & (__float_as_uint(pb.y) != POIS_U)
                     & (__float_as_uint(pb.z) != POIS_U) & (__float_as_uint(pb.w) != POIS_U);
        if (__all(ok)) break;
      }
      const float h0=pa.x,h1=pa.y,h2=pa.z,h3=pa.w,h4=pb.x,h5=pb.y,h6=pb.z,h7=pb.w;
#pragma unroll
      for (int r = 0; r < 16; ++r) {
        float a =            wv[2*r].x*h0;
        a = __builtin_fmaf(wv[2*r].y,  h1,a); a = __builtin_fmaf(wv[2*r].z,  h2,a);
        a = __builtin_fmaf(wv[2*r].w,  h3,a); a = __builtin_fmaf(wv[2*r+1].x,h4,a);
        a = __builtin_fmaf(wv[2*r+1].y,h5,a); a = __builtin_fmaf(wv[2*r+1].z,h6,a);
        a = __builtin_fmaf(wv[2*r+1].w,h7,a);
        acc[r] = a;
      }
    }

    // reduce-scatter: 16 row-partials over 64 lanes -> lane holds one row total
#pragma unroll
    for (int k = 0; k < 4; ++k) {
      const int m = 1 << k;
      const int half = 8 >> k;
      const bool up = (l & m) != 0;
#pragma unroll
      for (int t = 0; t < half; ++t) {
        const float mine = up ? acc[half+t] : acc[t];
        const float send = up ? acc[t] : acc[half+t];
        acc[t] = mine + __shfl_xor(send, m);
      }
    }
    float tot = acc[0];
    tot += __shfl_xor(tot, 16);
    tot += __shfl_xor(tot, 32);

    // gates for unit u = l&3 (all lanes compute redundantly; lanes 0-3 are canonical)
    const float gi = __shfl(tot, f_ + 0)  + xn0;
    const float gf = __shfl(tot, f_ + 8)  + xn1;
    const float gg = __shfl(tot, f_ + 4)  + xn2;
    const float go = __shfl(tot, f_ + 12) + xn3;
    const float iv = fsig_(gi), fv = fsig_(gf), zv = ftanh_(gg), ov = fsig_(go);
    cst = fv*cst + iv*zv;
    const float hval = ov * ftanh_(cst);
    if (l < 4) {
      float* dp = pdst + (size_t)s*HDIM;
      asm volatile("global_store_dword %0, %1, off sc0 sc1" :: "v"(dp), "v"(hval));
    }
    if (s+1 < S_LEN) {
      xptr += xstep;
      xn0 = __bfloat162float(xptr[0*HDIM]);
      xn1 = __bfloat162float(xptr[1*HDIM]);
      xn2 = __bfloat162float(xptr[2*HDIM]);
      xn3 = __bfloat162float(xptr[3*HDIM]);
    }
  }
}

// ---------- phase C: feats[s][t] = [hf,hb] . w_tag[t] + b_tag[t] ----------
// forward h_t = hbs[0][t]; backward h_t = hbs[1][S-1-t]
__global__ __launch_bounds__(64) void feats_ker(
    const float* __restrict__ hbs, const float* __restrict__ w_tag,
    const float* __restrict__ b_tag, float* __restrict__ feats)
{
  const int row = blockIdx.x;
  const int l = threadIdx.x;
  const float* __restrict__ hf  = hbs + (size_t)row*HDIM;
  const float* __restrict__ hbk = hbs + (size_t)S_LEN*HDIM + (size_t)(S_LEN-1-row)*HDIM;
  float a0=0,a1=0,a2=0,a3=0,a4=0;
#pragma unroll
  for (int i = 0; i < 8; ++i) {
    const int j = l + i*64;
    const float hfv = hf[j];
    const float hbv = hbk[j];
    a0 += hfv*w_tag[0*1024+j] + hbv*w_tag[0*1024+512+j];
    a1 += hfv*w_tag[1*1024+j] + hbv*w_tag[1*1024+512+j];
    a2 += hfv*w_tag[2*1024+j] + hbv*w_tag[2*1024+512+j];
    a3 += hfv*w_tag[3*1024+j] + hbv*w_tag[3*1024+512+j];
    a4 += hfv*w_tag[4*1024+j] + hbv*w_tag[4*1024+512+j];
  }
#pragma unroll
  for (int off = 32; off; off >>= 1) {
    a0 += __shfl_xor(a0, off); a1 += __shfl_xor(a1, off); a2 += __shfl_xor(a2, off);
    a3 += __shfl_xor(a3, off); a4 += __shfl_xor(a4, off);
  }
  if (l == 0) {
    feats[row*NTAG+0] = a0 + b_tag[0];
    feats[row*NTAG+1] = a1 + b_tag[1];
    feats[row*NTAG+2] = a2 + b_tag[2];
    feats[row*NTAG+3] = a3 + b_tag[3];
    feats[row*NTAG+4] = a4 + b_tag[4];
  }
}

// ---------- phase D: CRF log-partition as a log-semiring 5x5 matrix reduction + gold score ----------
__global__ __launch_bounds__(64) void crf_part(
    const float* __restrict__ feats, const float* __restrict__ trans,
    const int* __restrict__ tags, float* __restrict__ Mpart, float* __restrict__ gold_part)
{
  const int blk = blockIdx.x;         // 64 blocks x 64 steps
  const int l = threadIdx.x;
  const int s0 = blk * 64;
  const bool act = (l < 25);
  const int i = act ? (l/5) : 0;
  const int j = act ? (l%5) : 0;
  const float tT = trans[j*NTAG + i]; // M_s[i][j] = trans[j][i] + feats[s][j]
  float cur = tT + feats[(size_t)s0*NTAG + j];
  for (int s = s0+1; s < s0+64; ++s) {
    const float bv = tT + feats[(size_t)s*NTAG + j];
    cur = lse_mm(cur, bv, i, j);
  }
  if (act) Mpart[blk*25 + l] = cur;

  // gold partial: s = s0 + lane
  const int s = s0 + l;
  const int tg = tags[s];
  const int pv = (s == 0) ? START_TAG : tags[s-1];
  float gv = trans[tg*NTAG + pv] + feats[(size_t)s*NTAG + tg];
#pragma unroll
  for (int off = 32; off; off >>= 1) gv += __shfl_xor(gv, off);
  if (l == 0) gold_part[blk] = gv;
}

__global__ __launch_bounds__(64) void crf_final(
    const float* __restrict__ Mpart, const float* __restrict__ gold_part,
    const float* __restrict__ trans, const int* __restrict__ tags, float* __restrict__ out)
{
  const int l = threadIdx.x;
  const bool act = (l < 25);
  const int i = act ? (l/5) : 0;
  const int j = act ? (l%5) : 0;
  float cur = Mpart[act ? l : 0];
  for (int b = 1; b < 64; ++b) {
    const float bv = Mpart[b*25 + (act ? l : 0)];
    cur = lse_mm(cur, bv, i, j);
  }
  // fold alpha0 (0 at START, NEG elsewhere):  aF[j] = LSE_i(alpha0[i] + P[i][j])
  const float t0 = ((0==START_TAG)?0.f:NEGV) + __shfl(cur, 0*5 + j);
  const float t1 = ((1==START_TAG)?0.f:NEGV) + __shfl(cur, 1*5 + j);
  const float t2 = ((2==START_TAG)?0.f:NEGV) + __shfl(cur, 2*5 + j);
  const float t3 = ((3==START_TAG)?0.f:NEGV) + __shfl(cur, 3*5 + j);
  const float t4 = ((4==START_TAG)?0.f:NEGV) + __shfl(cur, 4*5 + j);
  const float aF = lse5(t0,t1,t2,t3,t4);       // lanes 0..4 hold aF[j=lane]
  const float f0 = __shfl(aF, 0) + trans[STOP_TAG*NTAG + 0];
  const float f1 = __shfl(aF, 1) + trans[STOP_TAG*NTAG + 1];
  const float f2 = __shfl(aF, 2) + trans[STOP_TAG*NTAG + 2];
  const float f3 = __shfl(aF, 3) + trans[STOP_TAG*NTAG + 3];
  const float f4 = __shfl(aF, 4) + trans[STOP_TAG*NTAG + 4];
  const float fwd = lse5(f0,f1,f2,f3,f4);
  float gv = gold_part[l];
#pragma unroll
  for (int off = 32; off; off >>= 1) gv += __shfl_xor(gv, off);
  if (l == 0) out[0] = fwd - (gv + trans[STOP_TAG*NTAG + tags[S_LEN-1]]);
}

// ---------- launcher ----------
extern "C" void kernel_launch(void* const* d_in, const int* in_sizes, int n_in,
                              void* d_out, int out_size, void* d_ws, size_t ws_size,
                              hipStream_t stream) {
  const int*   sentence = (const int*)d_in[0];
  const int*   tags     = (const int*)d_in[1];
  const float* emb      = (const float*)d_in[2];
  const float* w_ih_f   = (const float*)d_in[3];
  const float* w_hh_f   = (const float*)d_in[4];
  const float* b_ih_f   = (const float*)d_in[5];
  const float* b_hh_f   = (const float*)d_in[6];
  const float* w_ih_b   = (const float*)d_in[7];
  const float* w_hh_b   = (const float*)d_in[8];
  const float* b_ih_b   = (const float*)d_in[9];
  const float* b_hh_b   = (const float*)d_in[10];
  const float* w_tag    = (const float*)d_in[11];
  const float* b_tag    = (const float*)d_in[12];
  const float* trans    = (const float*)d_in[13];
  float* out = (float*)d_out;
  char* ws = (char*)d_ws;
  if (ws_size < WS_NEEDED) return;   // clean wrong-answer instead of OOB

  __hip_bfloat16* xp   = (__hip_bfloat16*)(ws + OFF_XP);
  float* hbs           = (float*)(ws + OFF_HBS);
  float* feats         = (float*)(ws + OFF_FEATS);
  float* Mpart         = (float*)(ws + OFF_MPART);
  float* gold_part     = (float*)(ws + OFF_GOLD);

  const int n4 = (2 * S_LEN * HDIM) / 4;
  fill_poison<<<dim3(1024), dim3(256), 0, stream>>>(hbs, n4);
  xp_gemm<<<dim3(512, 2, 1), dim3(256), 0, stream>>>(sentence, emb,
      w_ih_f, b_ih_f, b_hh_f, w_ih_b, b_ih_b, b_hh_b, xp);
  lstm_pers<<<dim3(32), dim3(512), 0, stream>>>(w_hh_f, w_hh_b, xp, hbs);
  feats_ker<<<dim3(4096), dim3(64), 0, stream>>>(hbs, w_tag, b_tag, feats);
  crf_part<<<dim3(64), dim3(64), 0, stream>>>(feats, trans, tags, Mpart, gold_part);
  crf_final<<<dim3(1), dim3(64), 0, stream>>>(Mpart, gold_part, trans, tags, out);
}

// Round 4
// 10447.791 us; speedup vs baseline: 2.2558x; 2.2558x over previous
//
#include <hip/hip_runtime.h>
#include <hip/hip_bf16.h>

#define S_LEN 4096
#define EDIM  300
#define HDIM  512
#define G4    2048
#define NTAG  5
#define NEGV  -10000.0f
#define START_TAG 3
#define STOP_TAG  4
#define L2E 1.4426950408889634f
#define LN2 0.6931471805599453f
#define POIS_U 0x7F7F7F7Fu

typedef __attribute__((ext_vector_type(4))) float f32x4;

// ---------- workspace layout (bytes) ----------
static constexpr size_t OFF_XP    = 0;                                   // bf16 [2][S][2048]
static constexpr size_t XP_BYTES  = (size_t)2 * S_LEN * G4 * 2;
static constexpr size_t OFF_HBS   = OFF_XP + XP_BYTES;                   // f32 [2][S][512] poison-polled h history
static constexpr size_t HBS_BYTES = (size_t)2 * S_LEN * HDIM * 4;
static constexpr size_t OFF_FEATS = OFF_HBS + HBS_BYTES;                 // f32 [S][5]
static constexpr size_t OFF_MPART = OFF_FEATS + (size_t)S_LEN * NTAG * 4;// f32 [64][25]
static constexpr size_t OFF_GOLD  = OFF_MPART + (size_t)64 * 25 * 4;     // f32 [64]
static constexpr size_t WS_NEEDED = OFF_GOLD + 256;

// ---------- helpers ----------
static __device__ __forceinline__ float fexp_(float x){ return __builtin_amdgcn_exp2f(x * L2E); }
static __device__ __forceinline__ float fsig_(float x){ return __builtin_amdgcn_rcpf(1.0f + fexp_(-x)); }
static __device__ __forceinline__ float ftanh_(float x){ return 1.0f - 2.0f*__builtin_amdgcn_rcpf(fexp_(2.0f*x) + 1.0f); }

static __device__ __forceinline__ float lse5(float t0,float t1,float t2,float t3,float t4){
  float m = fmaxf(fmaxf(fmaxf(t0,t1),fmaxf(t2,t3)),t4);
  float s = __builtin_amdgcn_exp2f((t0-m)*L2E) + __builtin_amdgcn_exp2f((t1-m)*L2E)
          + __builtin_amdgcn_exp2f((t2-m)*L2E) + __builtin_amdgcn_exp2f((t3-m)*L2E)
          + __builtin_amdgcn_exp2f((t4-m)*L2E);
  return m + __builtin_amdgcn_logf(s)*LN2;
}

// C[i][j] = LSE_k(cur[i][k] + bv[k][j]); lane layout: lane = i*5+j (lanes 0..24)
static __device__ __forceinline__ float lse_mm(float cur, float bv, int i, int j){
  const float a0=__shfl(cur, i*5+0), a1=__shfl(cur, i*5+1), a2=__shfl(cur, i*5+2),
              a3=__shfl(cur, i*5+3), a4=__shfl(cur, i*5+4);
  const float c0=__shfl(bv, 0+j),  c1=__shfl(bv, 5+j),  c2=__shfl(bv, 10+j),
              c3=__shfl(bv, 15+j), c4=__shfl(bv, 20+j);
  return lse5(a0+c0, a1+c1, a2+c2, a3+c3, a4+c4);
}

// ---------- phase 0: poison-fill hbs with coherent (sc0 sc1) stores so no dirty L2 lines exist ----------
__global__ __launch_bounds__(256) void fill_poison(float* __restrict__ p, int n4){
  const int idx = blockIdx.x*blockDim.x + threadIdx.x;
  const int stride = gridDim.x*blockDim.x;
  f32x4 pv;
  pv.x = __uint_as_float(POIS_U); pv.y = __uint_as_float(POIS_U);
  pv.z = __uint_as_float(POIS_U); pv.w = __uint_as_float(POIS_U);
  for (int i = idx; i < n4; i += stride) {
    float* dst = p + (size_t)i*4;
    asm volatile("global_store_dwordx4 %0, %1, off sc0 sc1" :: "v"(dst), "v"(pv) : "memory");
  }
}

// ---------- phase A: xp[dir][s][2048] = emb[sent[s]] @ w_ih.T + (b_ih+b_hh), stored bf16 ----------
__global__ __launch_bounds__(256) void xp_gemm(
    const int* __restrict__ sentence, const float* __restrict__ emb,
    const float* __restrict__ w_ih_f, const float* __restrict__ b_ih_f, const float* __restrict__ b_hh_f,
    const float* __restrict__ w_ih_b, const float* __restrict__ b_ih_b, const float* __restrict__ b_hh_b,
    __hip_bfloat16* __restrict__ xp)
{
  __shared__ float At[32][132];
  __shared__ float Bt[32][132];
  __shared__ int sent_s[128];

  const int dir = blockIdx.y;
  const int tm = blockIdx.x & 31;
  const int tn = blockIdx.x >> 5;
  const float* __restrict__ wih = dir ? w_ih_b : w_ih_f;
  const float* __restrict__ bi  = dir ? b_ih_b : b_ih_f;
  const float* __restrict__ bh  = dir ? b_hh_b : b_hh_f;

  const int tid = threadIdx.x;
  if (tid < 128) sent_s[tid] = sentence[tm*128 + tid];

  const int ty = tid >> 4, tx = tid & 15;
  const int li = tid >> 1, lh = tid & 1;

  float acc[8][8];
#pragma unroll
  for (int i = 0; i < 8; ++i){
#pragma unroll
    for (int j = 0; j < 8; ++j) acc[i][j] = 0.0f;
  }
  __syncthreads();

  for (int kc0 = 0; kc0 < EDIM; kc0 += 32) {
    const int kw = (EDIM - kc0 < 32) ? (EDIM - kc0) : 32;
    if (kc0 + lh*16 + 16 <= EDIM) {
      const float4* pa = (const float4*)(emb + (size_t)sent_s[li]*EDIM + kc0 + lh*16);
      const float4* pb = (const float4*)(wih + (size_t)(tn*128 + li)*EDIM + kc0 + lh*16);
#pragma unroll
      for (int v = 0; v < 4; ++v) {
        const float4 a = pa[v], b = pb[v];
        const int kk = lh*16 + v*4;
        At[kk+0][li] = a.x; At[kk+1][li] = a.y; At[kk+2][li] = a.z; At[kk+3][li] = a.w;
        Bt[kk+0][li] = b.x; Bt[kk+1][li] = b.y; Bt[kk+2][li] = b.z; Bt[kk+3][li] = b.w;
      }
    } else {
#pragma unroll
      for (int jj = 0; jj < 16; ++jj) {
        const int col = kc0 + lh*16 + jj;
        float av = 0.f, bv = 0.f;
        if (col < EDIM) {
          av = emb[(size_t)sent_s[li]*EDIM + col];
          bv = wih[(size_t)(tn*128 + li)*EDIM + col];
        }
        At[lh*16+jj][li] = av;
        Bt[lh*16+jj][li] = bv;
      }
    }
    __syncthreads();
#pragma unroll 4
    for (int k = 0; k < kw; ++k) {
      const float4 a0 = *(const float4*)&At[k][ty*8];
      const float4 a1 = *(const float4*)&At[k][ty*8+4];
      const float4 b0 = *(const float4*)&Bt[k][tx*8];
      const float4 b1 = *(const float4*)&Bt[k][tx*8+4];
      const float av[8] = {a0.x,a0.y,a0.z,a0.w,a1.x,a1.y,a1.z,a1.w};
      const float bv[8] = {b0.x,b0.y,b0.z,b0.w,b1.x,b1.y,b1.z,b1.w};
#pragma unroll
      for (int i = 0; i < 8; ++i){
#pragma unroll
        for (int j = 0; j < 8; ++j) acc[i][j] = __builtin_fmaf(av[i], bv[j], acc[i][j]);
      }
    }
    __syncthreads();
  }

  const int n0 = tn*128 + tx*8;
  float bias[8];
#pragma unroll
  for (int j = 0; j < 8; ++j) bias[j] = bi[n0+j] + bh[n0+j];

  __hip_bfloat16* __restrict__ xpd = xp + (size_t)dir * S_LEN * G4;
#pragma unroll
  for (int i = 0; i < 8; ++i) {
    const int m = tm*128 + ty*8 + i;
    __hip_bfloat16 __align__(16) tmp[8];
#pragma unroll
    for (int j = 0; j < 8; ++j) tmp[j] = __float2bfloat16(acc[i][j] + bias[j]);
    *(uint4*)(xpd + (size_t)m*G4 + n0) = *(const uint4*)tmp;
  }
}

// ---------- phase B: persistent BiLSTM, poison-poll sync, W streamed from L2 + prefetch-overlap ----------
// 256 wgs (128/dir), 256 threads (4 waves). Wave w_ owns global unit gu = wg*4+w_ (4 gate rows x 512 cols).
// Lane l owns h-cols [8l, 8l+8). Per step: 8 dwordx4 W loads (32 KB/wg from L2, issued EARLY so they
// overlap the h poll), 32 FMAs, 7-shuffle reduce-scatter, gates computed redundantly, lane 0 stores h.
// No __syncthreads, no flags, no fences: h values self-signal via poison pattern (sc0 sc1 ops).
#define WLOAD0(dst, p) asm volatile("global_load_dwordx4 %0, %1, off"            : "=v"(dst) : "v"(p))
#define WLOAD1(dst, p) asm volatile("global_load_dwordx4 %0, %1, off offset:16"  : "=v"(dst) : "v"(p))
#define ISSUE_W() do { \
    WLOAD0(w0a, wp0); WLOAD1(w0b, wp0); \
    WLOAD0(w1a, wp1); WLOAD1(w1b, wp1); \
    WLOAD0(w2a, wp2); WLOAD1(w2b, wp2); \
    WLOAD0(w3a, wp3); WLOAD1(w3b, wp3); \
  } while (0)

__global__ __launch_bounds__(256, 1) void lstm_pers(
    const float* __restrict__ w_hh_f, const float* __restrict__ w_hh_b,
    const __hip_bfloat16* __restrict__ xp, float* __restrict__ hbs)
{
  const int dir = blockIdx.x >> 7;
  const int wg  = blockIdx.x & 127;
  const int tid = threadIdx.x;
  const int w_  = tid >> 6;              // wave = local unit 0..3
  const int l   = tid & 63;
  const int gu  = wg*4 + w_;             // global unit 0..511

  const float* __restrict__ whh = dir ? w_hh_b : w_hh_f;
  const __hip_bfloat16* __restrict__ xpd = xp + (size_t)dir * S_LEN * G4;
  float* __restrict__ hbs_d = hbs + (size_t)dir * S_LEN * HDIM;

  // loop-invariant W row pointers (gate g row = g*HDIM + gu), cols [8l, 8l+8)
  const float* wp0 = whh + (size_t)(0*HDIM + gu)*HDIM + l*8;
  const float* wp1 = whh + (size_t)(1*HDIM + gu)*HDIM + l*8;
  const float* wp2 = whh + (size_t)(2*HDIM + gu)*HDIM + l*8;
  const float* wp3 = whh + (size_t)(3*HDIM + gu)*HDIM + l*8;

  const __hip_bfloat16* xptr = xpd + (size_t)(dir ? (S_LEN-1) : 0)*G4 + gu;
  const ptrdiff_t xstep = dir ? -(ptrdiff_t)G4 : (ptrdiff_t)G4;
  float xn0 = __bfloat162float(xptr[0*HDIM]);
  float xn1 = __bfloat162float(xptr[1*HDIM]);
  float xn2 = __bfloat162float(xptr[2*HDIM]);
  float xn3 = __bfloat162float(xptr[3*HDIM]);

  float cst = 0.0f;
  f32x4 w0a,w0b,w1a,w1b,w2a,w2b,w3a,w3b;
  ISSUE_W();                             // in flight for step 1; completes during step 0 + first poll

  // ---- step 0: tot = 0, gates from xp only
  {
    const float iv = fsig_(xn0), fv = fsig_(xn1), zv = ftanh_(xn2), ov = fsig_(xn3);
    cst = fv*0.0f + iv*zv;
    const float hval = ov * ftanh_(cst);
    if (l == 0) {
      float* dp = hbs_d + gu;
      asm volatile("global_store_dword %0, %1, off sc0 sc1" :: "v"(dp), "v"(hval));
    }
    xptr += xstep;
    xn0 = __bfloat162float(xptr[0*HDIM]);
    xn1 = __bfloat162float(xptr[1*HDIM]);
    xn2 = __bfloat162float(xptr[2*HDIM]);
    xn3 = __bfloat162float(xptr[3*HDIM]);
  }

#pragma clang loop unroll(disable)
  for (int s = 1; s < S_LEN; ++s) {
    // 1. poll h_{s-1} (8 floats per lane); vmcnt(0) inside also completes the W prefetch
    f32x4 pa, pb;
    const float* sp = hbs_d + (size_t)(s-1)*HDIM + l*8;
    for (int it = 0; it < (1<<18); ++it) {
      asm volatile(
        "global_load_dwordx4 %0, %2, off sc0 sc1\n\t"
        "global_load_dwordx4 %1, %2, off offset:16 sc0 sc1\n\t"
        "s_waitcnt vmcnt(0)"
        : "=&v"(pa), "=&v"(pb) : "v"(sp));
      const int ok = (__float_as_uint(pa.x) != POIS_U) & (__float_as_uint(pa.y) != POIS_U)
                   & (__float_as_uint(pa.z) != POIS_U) & (__float_as_uint(pa.w) != POIS_U)
                   & (__float_as_uint(pb.x) != POIS_U) & (__float_as_uint(pb.y) != POIS_U)
                   & (__float_as_uint(pb.z) != POIS_U) & (__float_as_uint(pb.w) != POIS_U);
      if (__all(ok)) break;
    }

    // 2. partial matvec: 4 gate rows x 8 cols
    float a0, a1, a2, a3;
    {
      const float h0=pa.x,h1=pa.y,h2=pa.z,h3=pa.w,h4=pb.x,h5=pb.y,h6=pb.z,h7=pb.w;
      a0 = w0a.x*h0; a0=__builtin_fmaf(w0a.y,h1,a0); a0=__builtin_fmaf(w0a.z,h2,a0); a0=__builtin_fmaf(w0a.w,h3,a0);
      a0=__builtin_fmaf(w0b.x,h4,a0); a0=__builtin_fmaf(w0b.y,h5,a0); a0=__builtin_fmaf(w0b.z,h6,a0); a0=__builtin_fmaf(w0b.w,h7,a0);
      a1 = w1a.x*h0; a1=__builtin_fmaf(w1a.y,h1,a1); a1=__builtin_fmaf(w1a.z,h2,a1); a1=__builtin_fmaf(w1a.w,h3,a1);
      a1=__builtin_fmaf(w1b.x,h4,a1); a1=__builtin_fmaf(w1b.y,h5,a1); a1=__builtin_fmaf(w1b.z,h6,a1); a1=__builtin_fmaf(w1b.w,h7,a1);
      a2 = w2a.x*h0; a2=__builtin_fmaf(w2a.y,h1,a2); a2=__builtin_fmaf(w2a.z,h2,a2); a2=__builtin_fmaf(w2a.w,h3,a2);
      a2=__builtin_fmaf(w2b.x,h4,a2); a2=__builtin_fmaf(w2b.y,h5,a2); a2=__builtin_fmaf(w2b.z,h6,a2); a2=__builtin_fmaf(w2b.w,h7,a2);
      a3 = w3a.x*h0; a3=__builtin_fmaf(w3a.y,h1,a3); a3=__builtin_fmaf(w3a.z,h2,a3); a3=__builtin_fmaf(w3a.w,h3,a3);
      a3=__builtin_fmaf(w3b.x,h4,a3); a3=__builtin_fmaf(w3b.y,h5,a3); a3=__builtin_fmaf(w3b.z,h6,a3); a3=__builtin_fmaf(w3b.w,h7,a3);
    }

    // 3. re-issue W loads for step s+1 — same addresses, value-identical, overlaps everything below
    if (s + 1 < S_LEN) ISSUE_W();

    // 4. reduce-scatter 4 rows over 64 lanes (7 shuffle-adds); row r=2*(l&1)+((l>>1)&1)
    {
      const bool u1 = (l & 1) != 0;
      float m0 = u1 ? a2 : a0, s0_ = u1 ? a0 : a2;
      float m1 = u1 ? a3 : a1, s1_ = u1 ? a1 : a3;
      const float b0 = m0 + __shfl_xor(s0_, 1);
      const float b1 = m1 + __shfl_xor(s1_, 1);
      const bool u2 = (l & 2) != 0;
      float m2 = u2 ? b1 : b0, s2_ = u2 ? b0 : b1;
      float tot = m2 + __shfl_xor(s2_, 2);
      tot += __shfl_xor(tot, 4);
      tot += __shfl_xor(tot, 8);
      tot += __shfl_xor(tot, 16);
      tot += __shfl_xor(tot, 32);

      // 5. gates (rows: 0=i@lane0, 1=f@lane2, 2=g@lane1, 3=o@lane3), all lanes redundant
      const float gi = __shfl(tot, 0) + xn0;
      const float gf = __shfl(tot, 2) + xn1;
      const float gg = __shfl(tot, 1) + xn2;
      const float go = __shfl(tot, 3) + xn3;
      const float iv = fsig_(gi), fv = fsig_(gf), zv = ftanh_(gg), ov = fsig_(go);
      cst = fv*cst + iv*zv;
      const float hval = ov * ftanh_(cst);
      if (l == 0) {
        float* dp = hbs_d + (size_t)s*HDIM + gu;
        asm volatile("global_store_dword %0, %1, off sc0 sc1" :: "v"(dp), "v"(hval));
      }
    }

    // 6. prefetch next step's xp gate values (off the critical path)
    if (s + 1 < S_LEN) {
      xptr += xstep;
      xn0 = __bfloat162float(xptr[0*HDIM]);
      xn1 = __bfloat162float(xptr[1*HDIM]);
      xn2 = __bfloat162float(xptr[2*HDIM]);
      xn3 = __bfloat162float(xptr[3*HDIM]);
    }
  }
}

// ---------- phase C: feats[s][t] = [hf,hb] . w_tag[t] + b_tag[t] ----------
// forward h_t = hbs[0][t]; backward h_t = hbs[1][S-1-t]
__global__ __launch_bounds__(64) void feats_ker(
    const float* __restrict__ hbs, const float* __restrict__ w_tag,
    const float* __restrict__ b_tag, float* __restrict__ feats)
{
  const int row = blockIdx.x;
  const int l = threadIdx.x;
  const float* __restrict__ hf  = hbs + (size_t)row*HDIM;
  const float* __restrict__ hbk = hbs + (size_t)S_LEN*HDIM + (size_t)(S_LEN-1-row)*HDIM;
  float a0=0,a1=0,a2=0,a3=0,a4=0;
#pragma unroll
  for (int i = 0; i < 8; ++i) {
    const int j = l + i*64;
    const float hfv = hf[j];
    const float hbv = hbk[j];
    a0 += hfv*w_tag[0*1024+j] + hbv*w_tag[0*1024+512+j];
    a1 += hfv*w_tag[1*1024+j] + hbv*w_tag[1*1024+512+j];
    a2 += hfv*w_tag[2*1024+j] + hbv*w_tag[2*1024+512+j];
    a3 += hfv*w_tag[3*1024+j] + hbv*w_tag[3*1024+512+j];
    a4 += hfv*w_tag[4*1024+j] + hbv*w_tag[4*1024+512+j];
  }
#pragma unroll
  for (int off = 32; off; off >>= 1) {
    a0 += __shfl_xor(a0, off); a1 += __shfl_xor(a1, off); a2 += __shfl_xor(a2, off);
    a3 += __shfl_xor(a3, off); a4 += __shfl_xor(a4, off);
  }
  if (l == 0) {
    feats[row*NTAG+0] = a0 + b_tag[0];
    feats[row*NTAG+1] = a1 + b_tag[1];
    feats[row*NTAG+2] = a2 + b_tag[2];
    feats[row*NTAG+3] = a3 + b_tag[3];
    feats[row*NTAG+4] = a4 + b_tag[4];
  }
}

// ---------- phase D: CRF log-partition as a log-semiring 5x5 matrix reduction + gold score ----------
__global__ __launch_bounds__(64) void crf_part(
    const float* __restrict__ feats, const float* __restrict__ trans,
    const int* __restrict__ tags, float* __restrict__ Mpart, float* __restrict__ gold_part)
{
  const int blk = blockIdx.x;         // 64 blocks x 64 steps
  const int l = threadIdx.x;
  const int s0 = blk * 64;
  const bool act = (l < 25);
  const int i = act ? (l/5) : 0;
  const int j = act ? (l%5) : 0;
  const float tT = trans[j*NTAG + i]; // M_s[i][j] = trans[j][i] + feats[s][j]
  float cur = tT + feats[(size_t)s0*NTAG + j];
  for (int s = s0+1; s < s0+64; ++s) {
    const float bv = tT + feats[(size_t)s*NTAG + j];
    cur = lse_mm(cur, bv, i, j);
  }
  if (act) Mpart[blk*25 + l] = cur;

  // gold partial: s = s0 + lane
  const int s = s0 + l;
  const int tg = tags[s];
  const int pv = (s == 0) ? START_TAG : tags[s-1];
  float gv = trans[tg*NTAG + pv] + feats[(size_t)s*NTAG + tg];
#pragma unroll
  for (int off = 32; off; off >>= 1) gv += __shfl_xor(gv, off);
  if (l == 0) gold_part[blk] = gv;
}

__global__ __launch_bounds__(64) void crf_final(
    const float* __restrict__ Mpart, const float* __restrict__ gold_part,
    const float* __restrict__ trans, const int* __restrict__ tags, float* __restrict__ out)
{
  const int l = threadIdx.x;
  const bool act = (l < 25);
  const int i = act ? (l/5) : 0;
  const int j = act ? (l%5) : 0;
  float cur = Mpart[act ? l : 0];
  for (int b = 1; b < 64; ++b) {
    const float bv = Mpart[b*25 + (act ? l : 0)];
    cur = lse_mm(cur, bv, i, j);
  }
  // fold alpha0 (0 at START, NEG elsewhere):  aF[j] = LSE_i(alpha0[i] + P[i][j])
  const float t0 = ((0==START_TAG)?0.f:NEGV) + __shfl(cur, 0*5 + j);
  const float t1 = ((1==START_TAG)?0.f:NEGV) + __shfl(cur, 1*5 + j);
  const float t2 = ((2==START_TAG)?0.f:NEGV) + __shfl(cur, 2*5 + j);
  const float t3 = ((3==START_TAG)?0.f:NEGV) + __shfl(cur, 3*5 + j);
  const float t4 = ((4==START_TAG)?0.f:NEGV) + __shfl(cur, 4*5 + j);
  const float aF = lse5(t0,t1,t2,t3,t4);       // lanes 0..4 hold aF[j=lane]
  const float f0 = __shfl(aF, 0) + trans[STOP_TAG*NTAG + 0];
  const float f1 = __shfl(aF, 1) + trans[STOP_TAG*NTAG + 1];
  const float f2 = __shfl(aF, 2) + trans[STOP_TAG*NTAG + 2];
  const float f3 = __shfl(aF, 3) + trans[STOP_TAG*NTAG + 3];
  const float f4 = __shfl(aF, 4) + trans[STOP_TAG*NTAG + 4];
  const float fwd = lse5(f0,f1,f2,f3,f4);
  float gv = gold_part[l];
#pragma unroll
  for (int off = 32; off; off >>= 1) gv += __shfl_xor(gv, off);
  if (l == 0) out[0] = fwd - (gv + trans[STOP_TAG*NTAG + tags[S_LEN-1]]);
}

// ---------- launcher ----------
extern "C" void kernel_launch(void* const* d_in, const int* in_sizes, int n_in,
                              void* d_out, int out_size, void* d_ws, size_t ws_size,
                              hipStream_t stream) {
  const int*   sentence = (const int*)d_in[0];
  const int*   tags     = (const int*)d_in[1];
  const float* emb      = (const float*)d_in[2];
  const float* w_ih_f   = (const float*)d_in[3];
  const float* w_hh_f   = (const float*)d_in[4];
  const float* b_ih_f   = (const float*)d_in[5];
  const float* b_hh_f   = (const float*)d_in[6];
  const float* w_ih_b   = (const float*)d_in[7];
  const float* w_hh_b   = (const float*)d_in[8];
  const float* b_ih_b   = (const float*)d_in[9];
  const float* b_hh_b   = (const float*)d_in[10];
  const float* w_tag    = (const float*)d_in[11];
  const float* b_tag    = (const float*)d_in[12];
  const float* trans    = (const float*)d_in[13];
  float* out = (float*)d_out;
  char* ws = (char*)d_ws;
  if (ws_size < WS_NEEDED) return;   // clean wrong-answer instead of OOB

  __hip_bfloat16* xp   = (__hip_bfloat16*)(ws + OFF_XP);
  float* hbs           = (float*)(ws + OFF_HBS);
  float* feats         = (float*)(ws + OFF_FEATS);
  float* Mpart         = (float*)(ws + OFF_MPART);
  float* gold_part     = (float*)(ws + OFF_GOLD);

  const int n4 = (2 * S_LEN * HDIM) / 4;
  fill_poison<<<dim3(1024), dim3(256), 0, stream>>>(hbs, n4);
  xp_gemm<<<dim3(512, 2, 1), dim3(256), 0, stream>>>(sentence, emb,
      w_ih_f, b_ih_f, b_hh_f, w_ih_b, b_ih_b, b_hh_b, xp);
  lstm_pers<<<dim3(256), dim3(256), 0, stream>>>(w_hh_f, w_hh_b, xp, hbs);
  feats_ker<<<dim3(4096), dim3(64), 0, stream>>>(hbs, w_tag, b_tag, feats);
  crf_part<<<dim3(64), dim3(64), 0, stream>>>(feats, trans, tags, Mpart, gold_part);
  crf_final<<<dim3(1), dim3(64), 0, stream>>>(Mpart, gold_part, trans, tags, out);
}